// Round 15
// baseline (846.881 us; speedup 1.0000x reference)
//
#include <hip/hip_runtime.h>
#include <hip/hip_bf16.h>
#include <math.h>

#define SCAN_B 256

typedef __attribute__((ext_vector_type(8))) short bf16x8;   // 8 bf16 = 4 VGPR
typedef __attribute__((ext_vector_type(4))) float f32x4;

__device__ __forceinline__ unsigned short f2bf(float f) {
    __hip_bfloat16 h = __float2bfloat16(f);   // RNE
    return *(unsigned short*)&h;
}
__device__ __forceinline__ float bf2f(unsigned short u) {
    unsigned v = ((unsigned)u) << 16;
    return __uint_as_float(v);
}
__device__ __forceinline__ float lrelu(float x) { return (x >= 0.f) ? x : 0.2f * x; }

// blend two packed bf16 pairs: r = bf16(c0*a + c1*b) lane-wise
__device__ __forceinline__ unsigned blend2(unsigned a, unsigned b, float c0, float c1) {
    float alo = bf2f((unsigned short)(a & 0xffff)), ahi = bf2f((unsigned short)(a >> 16));
    float blo = bf2f((unsigned short)(b & 0xffff)), bhi = bf2f((unsigned short)(b >> 16));
    unsigned short rlo = f2bf(c0 * alo + c1 * blo);
    unsigned short rhi = f2bf(c0 * ahi + c1 * bhi);
    return (unsigned)rlo | ((unsigned)rhi << 16);
}

// =============== MFMA GEMM: A[*,256] @ B^T[256n,256k]bf16 ===============
// 128x256 tile, BK=32, 8 K-steps, DOUBLE-BUFFERED LDS (2 x 24KB):
//   A[128][32]bf16 @ +0 (8KB), B^T[256][32]bf16 @ +8192 (16KB) per buffer.
// 2-phase pipeline: issue next tile's A global-loads BEFORE computing current
// tile (latency hides under MFMA+ds_read), ds_write after the barrier.
// Swizzle for 64B rows: slot ^ ((row>>1)&3)  -> 2-way/balanced on b128 r/w.
// MODE 0: outh = bf16(A@B + bias) + fused per-head logits (AF32: A is f32)
// MODE 1: A by blockIdx.y; atomicAdd(scoreSlot[y], sum_rows q.tanh(A@B+bias))
// MODE 2: A' = bf16(attn0*A + attn1*A2) at stage; outf[row] = relu-dot + b2
template<int MODE, int NV, int AF32>
__launch_bounds__(512, 6)
__global__ void gemm_mfma(const float* __restrict__ Af32,
                          const unsigned short* __restrict__ Abf,
                          const unsigned short* __restrict__ A2bf,
                          const unsigned short* __restrict__ Bt,
                          const float* __restrict__ bias,
                          const float* __restrict__ vq,
                          const float* __restrict__ b2p,
                          const float* __restrict__ attn2,
                          unsigned short* __restrict__ outh,
                          float* __restrict__ outf,
                          float* __restrict__ scoreSlot,
                          const float* __restrict__ av0,
                          const float* __restrict__ av1,
                          const float* __restrict__ av2,
                          float* __restrict__ lo0,
                          float* __restrict__ lo1,
                          float* __restrict__ lo2,
                          int M)
{
    __shared__ __align__(16) char sm[49152];   // two 24576-byte buffers
    __shared__ float red8[8];
    const int t    = threadIdx.x;
    const int lane = t & 63, wid = t >> 6;
    const int wr = wid >> 2, wc = wid & 3;
    const long row0 = (long)blockIdx.x * 128;
    const char* Ab = (const char*)((MODE == 1 && blockIdx.y == 1) ? A2bf : Abf);
    const char* A2 = (const char*)A2bf;
    const char* Bb = (const char*)Bt;

    float blend0 = 0.f, blend1 = 0.f;
    if (MODE == 2) { blend0 = attn2[0]; blend1 = attn2[1]; }

    // staging geometry: A = 128 rows x 4 slots(16B); B = 256 rows x 4 slots, 2 reps
    const int ar = t >> 2, aslot = t & 3;
    const long agrow = row0 + ar;
    const unsigned swA  = ((unsigned)(aslot << 4)) ^ ((unsigned)(((ar  >> 1) & 3) << 4));
    const int bn0 = t >> 2, bn1 = 128 + (t >> 2);
    const unsigned swB  = ((unsigned)(aslot << 4)) ^ ((unsigned)(((bn0 >> 1) & 3) << 4));
    // (bn1 = bn0+128 -> same (row>>1)&3 -> same swizzle)

    f32x4 acc[4][4];
#pragma unroll
    for (int m = 0; m < 4; ++m)
#pragma unroll
        for (int n = 0; n < 4; ++n) acc[m][n] = (f32x4){0.f, 0.f, 0.f, 0.f};

    float4 rF0, rF1;     // AF32 A-prefetch
    uint4  rA, rA2;      // bf16 A-prefetch

    auto loadA = [&](int k0) {
        if (AF32) {
            rF0 = make_float4(0.f, 0.f, 0.f, 0.f); rF1 = rF0;
            if (agrow < M) {
                const float* sp = Af32 + agrow * 256 + k0 + aslot * 8;
                rF0 = *(const float4*)sp;
                rF1 = *(const float4*)(sp + 4);
            }
        } else {
            rA = *(const uint4*)(Ab + agrow * 512 + (long)k0 * 2 + aslot * 16);
            if (MODE == 2)
                rA2 = *(const uint4*)(A2 + agrow * 512 + (long)k0 * 2 + aslot * 16);
        }
    };
    auto stage = [&](char* buf, int k0) {
        uint4 v;
        if (AF32) {
            v.x = (unsigned)f2bf(rF0.x) | ((unsigned)f2bf(rF0.y) << 16);
            v.y = (unsigned)f2bf(rF0.z) | ((unsigned)f2bf(rF0.w) << 16);
            v.z = (unsigned)f2bf(rF1.x) | ((unsigned)f2bf(rF1.y) << 16);
            v.w = (unsigned)f2bf(rF1.z) | ((unsigned)f2bf(rF1.w) << 16);
        } else if (MODE == 2) {
            v.x = blend2(rA.x, rA2.x, blend0, blend1);
            v.y = blend2(rA.y, rA2.y, blend0, blend1);
            v.z = blend2(rA.z, rA2.z, blend0, blend1);
            v.w = blend2(rA.w, rA2.w, blend0, blend1);
        } else {
            v = rA;
        }
        *(uint4*)(buf + ar * 64 + swA) = v;
        uint4 b0 = *(const uint4*)(Bb + (long)bn0 * 512 + (long)k0 * 2 + aslot * 16);
        uint4 b1 = *(const uint4*)(Bb + (long)bn1 * 512 + (long)k0 * 2 + aslot * 16);
        *(uint4*)(buf + 8192 + bn0 * 64 + swB) = b0;
        *(uint4*)(buf + 8192 + bn1 * 64 + swB) = b1;
    };
    auto compute = [&](const char* buf) {
        const int kb = (lane >> 4) << 4;
        bf16x8 a[4], b[4];
#pragma unroll
        for (int m = 0; m < 4; ++m) {
            int row = wr * 64 + m * 16 + (lane & 15);
            a[m] = *(const bf16x8*)(buf + row * 64 + (kb ^ (((row >> 1) & 3) << 4)));
        }
#pragma unroll
        for (int n = 0; n < 4; ++n) {
            int nr = wc * 64 + n * 16 + (lane & 15);
            b[n] = *(const bf16x8*)(buf + 8192 + nr * 64 + (kb ^ (((nr >> 1) & 3) << 4)));
        }
#pragma unroll
        for (int m = 0; m < 4; ++m)
#pragma unroll
            for (int n = 0; n < 4; ++n)
                acc[m][n] = __builtin_amdgcn_mfma_f32_16x16x32_bf16(a[m], b[n], acc[m][n], 0, 0, 0);
    };

    // ---- 2-phase pipelined K loop ----
    loadA(0);
    stage(sm, 0);
    __syncthreads();
#pragma unroll
    for (int kt = 0; kt < 8; ++kt) {
        if (kt < 7) loadA((kt + 1) * 32);          // issue early: hides under compute
        compute(sm + (kt & 1) * 24576);
        __syncthreads();                            // all waves done reading other buf
        if (kt < 7) {
            stage(sm + ((kt + 1) & 1) * 24576, (kt + 1) * 32);
            __syncthreads();
        }
    }

    const int colbase = wc * 64 + (lane & 15);
    const int rbase   = wr * 64 + ((lane >> 4) << 2);
    float bv[4];
#pragma unroll
    for (int n = 0; n < 4; ++n) bv[n] = bias[colbase + n * 16];

    if (MODE == 0) {
        float areg[(NV > 0) ? NV : 1][4];
#pragma unroll
        for (int v = 0; v < NV; ++v) {
            const float* av = (v == 0) ? av0 : (v == 1) ? av1 : av2;
#pragma unroll
            for (int n = 0; n < 4; ++n) areg[v][n] = av[colbase + n * 16];
        }
#pragma unroll
        for (int m = 0; m < 4; ++m) {
#pragma unroll
            for (int j = 0; j < 4; ++j) {
                long row = row0 + rbase + m * 16 + j;
                float hv[4];
#pragma unroll
                for (int n = 0; n < 4; ++n) hv[n] = acc[m][n][j] + bv[n];
                if (row < M) {
#pragma unroll
                    for (int n = 0; n < 4; ++n)
                        outh[row * 256 + colbase + n * 16] = f2bf(hv[n]);
                }
#pragma unroll
                for (int v = 0; v < NV; ++v) {
                    float p = hv[0] * areg[v][0] + hv[1] * areg[v][1]
                            + hv[2] * areg[v][2] + hv[3] * areg[v][3];
                    p += __shfl_xor(p, 1); p += __shfl_xor(p, 2);
                    p += __shfl_xor(p, 4); p += __shfl_xor(p, 8);
                    if ((lane & 15) == 0 && row < M) {
                        float* lo = (v == 0) ? lo0 : (v == 1) ? lo1 : lo2;
                        lo[row * 4 + wc] = p;
                    }
                }
            }
        }
    } else if (MODE == 1) {
        float p = 0.f;
        float qv[4];
#pragma unroll
        for (int n = 0; n < 4; ++n) qv[n] = vq[colbase + n * 16];
#pragma unroll
        for (int n = 0; n < 4; ++n) {
#pragma unroll
            for (int m = 0; m < 4; ++m) {
                long row = row0 + rbase + m * 16;
#pragma unroll
                for (int j = 0; j < 4; ++j)
                    if (row + j < M) p += qv[n] * tanhf(acc[m][n][j] + bv[n]);
            }
        }
#pragma unroll
        for (int off = 32; off > 0; off >>= 1) p += __shfl_xor(p, off);
        if (lane == 0) red8[wid] = p;
        __syncthreads();
        if (t == 0) {
            float s = 0.f;
#pragma unroll
            for (int i = 0; i < 8; ++i) s += red8[i];
            atomicAdd(&scoreSlot[blockIdx.y], s);
        }
    } else {
        float* redC = (float*)sm;   // reuse tile buffer (barrier already executed)
        float b2v = b2p[0];
        float wv[4];
#pragma unroll
        for (int n = 0; n < 4; ++n) wv[n] = vq[colbase + n * 16];
#pragma unroll
        for (int m = 0; m < 4; ++m) {
#pragma unroll
            for (int j = 0; j < 4; ++j) {
                float s = 0.f;
#pragma unroll
                for (int n = 0; n < 4; ++n)
                    s += fmaxf(acc[m][n][j] + bv[n], 0.f) * wv[n];
                s += __shfl_xor(s, 1); s += __shfl_xor(s, 2);
                s += __shfl_xor(s, 4); s += __shfl_xor(s, 8);
                if ((lane & 15) == 0) {
                    int lrow = wr * 64 + m * 16 + ((lane >> 4) << 2) + j;
                    redC[lrow * 4 + wc] = s;
                }
            }
        }
        __syncthreads();
        if (t < 128) {
            long row = row0 + t;
            if (row < M)
                outf[row] = redC[t * 4 + 0] + redC[t * 4 + 1]
                          + redC[t * 4 + 2] + redC[t * 4 + 3] + b2v;
        }
    }
}

// ---------------- merged weight transposes: Wt[n][k] = bf16(W[k][n]) ----------------
__global__ void transpose_cast4(const float* __restrict__ W0, const float* __restrict__ W1s,
                                const float* __restrict__ W2s, const float* __restrict__ W3s,
                                unsigned short* __restrict__ T0, unsigned short* __restrict__ T1,
                                unsigned short* __restrict__ T2, unsigned short* __restrict__ T3)
{
    const float* W = (blockIdx.y == 0) ? W0 : (blockIdx.y == 1) ? W1s : (blockIdx.y == 2) ? W2s : W3s;
    unsigned short* T = (blockIdx.y == 0) ? T0 : (blockIdx.y == 1) ? T1 : (blockIdx.y == 2) ? T2 : T3;
    int n = blockIdx.x, k = threadIdx.x;
    T[n * 256 + k] = f2bf(W[k * 256 + n]);
}

// ---------------- CSR build (both edge types via blockIdx.y) ----------------
__global__ void hist2(const int* __restrict__ d0, int E0, int* __restrict__ g0,
                      const int* __restrict__ d1, int E1, int* __restrict__ g1)
{
    int e = blockIdx.x * 256 + threadIdx.x;
    if (blockIdx.y == 0) { if (e < E0) atomicAdd(&g0[d0[e]], 1); }
    else                 { if (e < E1) atomicAdd(&g1[d1[e]], 1); }
}

__global__ void scan_bsum2(const int* __restrict__ g0, const int* __restrict__ g1, int n,
                           int* __restrict__ p0, int* __restrict__ p1)
{
    const int* deg = blockIdx.y ? g1 : g0;
    int* part      = blockIdx.y ? p1 : p0;
    __shared__ int smem[SCAN_B];
    int i = blockIdx.x * SCAN_B + threadIdx.x;
    smem[threadIdx.x] = (i < n) ? deg[i] : 0;
    __syncthreads();
    for (int off = SCAN_B / 2; off > 0; off >>= 1) {
        if (threadIdx.x < off) smem[threadIdx.x] += smem[threadIdx.x + off];
        __syncthreads();
    }
    if (threadIdx.x == 0) part[blockIdx.x] = smem[0];
}

__global__ void scan_part2(int* __restrict__ p0, int* __restrict__ p1, int nb)
{
    int* part = blockIdx.y ? p1 : p0;
    __shared__ int smem[1024];
    int t = threadIdx.x;
    int v = (t < nb) ? part[t] : 0;
    smem[t] = v;
    __syncthreads();
    for (int off = 1; off < 1024; off <<= 1) {
        int add = (t >= off) ? smem[t - off] : 0;
        __syncthreads();
        smem[t] += add;
        __syncthreads();
    }
    if (t < nb) part[t] = smem[t] - v;
}

__global__ void scan_final2(const int* __restrict__ g0, const int* __restrict__ g1, int n,
                            const int* __restrict__ p0, const int* __restrict__ p1,
                            int* __restrict__ r0, int* __restrict__ r1, int E0, int E1)
{
    const int* deg = blockIdx.y ? g1 : g0;
    const int* part = blockIdx.y ? p1 : p0;
    int* rowptr = blockIdx.y ? r1 : r0;
    int E = blockIdx.y ? E1 : E0;
    __shared__ int smem[SCAN_B];
    int t = threadIdx.x;
    int i = blockIdx.x * SCAN_B + t;
    int v = (i < n) ? deg[i] : 0;
    smem[t] = v;
    __syncthreads();
    for (int off = 1; off < SCAN_B; off <<= 1) {
        int add = (t >= off) ? smem[t - off] : 0;
        __syncthreads();
        smem[t] += add;
        __syncthreads();
    }
    if (i < n) rowptr[i] = part[blockIdx.x] + smem[t] - v;
    if (blockIdx.x == 0 && t == 0) rowptr[n] = E;
}

// fill CSR slots with the SOURCE NODE ID directly (not the edge id)
__global__ void fill_csr2(const int* __restrict__ d0, const int* __restrict__ s0arr, int E0,
                          const int* __restrict__ r0, int* __restrict__ c0, int* __restrict__ o0,
                          const int* __restrict__ d1, const int* __restrict__ s1arr, int E1,
                          const int* __restrict__ r1, int* __restrict__ c1, int* __restrict__ o1)
{
    int e = blockIdx.x * 256 + threadIdx.x;
    if (blockIdx.y == 0) {
        if (e < E0) { int d = d0[e]; int s = atomicAdd(&c0[d], 1); o0[r0[d] + s] = s0arr[e]; }
    } else {
        if (e < E1) { int d = d1[e]; int s = atomicAdd(&c1[d], 1); o1[r1[d] + s] = s1arr[e]; }
    }
}

// ======== fused per-dst GAT (merged over gridDim.y = 2 edge types) ========
// one wave per dst node; bf16 x tables; CSR slots hold src ids (2-deep chain).
// NO-MAX softmax (logits bounded); denominator folded into the gather loop.
// lw stored TRANSPOSED [head][edge]; 4-edge inner loop reads 4 weights + 4 src
// ids as two ds_read_b128 (16-lane broadcast groups).
__launch_bounds__(256)
__global__ void gat_fused(const unsigned short* __restrict__ xs0,
                          const unsigned short* __restrict__ xs1,
                          const float* __restrict__ als0, const float* __restrict__ als1,
                          const float* __restrict__ ald0, const float* __restrict__ ald1,
                          const int* __restrict__ rp0, const int* __restrict__ rp1,
                          const int* __restrict__ csr0, const int* __restrict__ csr1,
                          int N,
                          unsigned short* __restrict__ out0,
                          unsigned short* __restrict__ out1)
{
    const int et = blockIdx.y;
    const unsigned short* xsrc = et ? xs1 : xs0;
    const float* als = et ? als1 : als0;
    const float* ald = et ? ald1 : ald0;
    const int* rowptr = et ? rp1 : rp0;
    const int* csr    = et ? csr1 : csr0;
    unsigned short* outb = et ? out1 : out0;

    __shared__ __align__(16) float lw[4][4 * 64];   // [wave][head*64 + edge]
    __shared__ __align__(16) int   ls[4][64];
    const int wv   = threadIdx.x >> 6;
    const int w    = (int)((blockIdx.x * 256 + threadIdx.x) >> 6);
    const int lane = threadIdx.x & 63;
    if (w >= N) return;
    const int beg = rowptr[w], end = rowptr[w + 1];
    const int deg = end - beg;
    const int h = lane >> 4;
    const float4 d4 = *(const float4*)&ald[(size_t)w * 4];
    const unsigned loffb = (unsigned)(lane << 3);          // byte offset of lane's 4 bf16
    const char* xb = (const char*)xsrc;

    float accA[4] = {0.f, 0.f, 0.f, 0.f};
    float accB[4] = {0.f, 0.f, 0.f, 0.f};
    float dn = 0.f;

    if (deg <= 64) {
        if (lane < deg) {
            int es = csr[beg + lane];                 // src id directly
            float4 a = *(const float4*)&als[(size_t)es * 4];
            ls[wv][lane] = es;
            lw[wv][0 * 64 + lane] = __expf(lrelu(a.x + d4.x));
            lw[wv][1 * 64 + lane] = __expf(lrelu(a.y + d4.y));
            lw[wv][2 * 64 + lane] = __expf(lrelu(a.z + d4.z));
            lw[wv][3 * 64 + lane] = __expf(lrelu(a.w + d4.w));
        }
        int i = 0;
        for (; i + 4 <= deg; i += 4) {
            int4   s4  = *(const int4*)&ls[wv][i];
            float4 wx4 = *(const float4*)&lw[wv][h * 64 + i];
            ushort4 x0 = *(const ushort4*)(xb + ((unsigned)s4.x * 512u + loffb));
            ushort4 x1 = *(const ushort4*)(xb + ((unsigned)s4.y * 512u + loffb));
            ushort4 x2 = *(const ushort4*)(xb + ((unsigned)s4.z * 512u + loffb));
            ushort4 x3 = *(const ushort4*)(xb + ((unsigned)s4.w * 512u + loffb));
            dn += wx4.x + wx4.y + wx4.z + wx4.w;
            accA[0] += wx4.x * bf2f(x0.x); accA[1] += wx4.x * bf2f(x0.y);
            accA[2] += wx4.x * bf2f(x0.z); accA[3] += wx4.x * bf2f(x0.w);
            accB[0] += wx4.y * bf2f(x1.x); accB[1] += wx4.y * bf2f(x1.y);
            accB[2] += wx4.y * bf2f(x1.z); accB[3] += wx4.y * bf2f(x1.w);
            accA[0] += wx4.z * bf2f(x2.x); accA[1] += wx4.z * bf2f(x2.y);
            accA[2] += wx4.z * bf2f(x2.z); accA[3] += wx4.z * bf2f(x2.w);
            accB[0] += wx4.w * bf2f(x3.x); accB[1] += wx4.w * bf2f(x3.y);
            accB[2] += wx4.w * bf2f(x3.z); accB[3] += wx4.w * bf2f(x3.w);
        }
        for (; i < deg; ++i) {
            int s = ls[wv][i];
            float wx = lw[wv][h * 64 + i];
            ushort4 xu = *(const ushort4*)(xb + ((unsigned)s * 512u + loffb));
            dn += wx;
            accA[0] += wx * bf2f(xu.x); accA[1] += wx * bf2f(xu.y);
            accA[2] += wx * bf2f(xu.z); accA[3] += wx * bf2f(xu.w);
        }
    } else {
        for (int c = beg; c < end; c += 64) {
            int cnt = min(64, end - c);
            if (lane < cnt) {
                int es = csr[c + lane];
                float4 a = *(const float4*)&als[(size_t)es * 4];
                ls[wv][lane] = es;
                lw[wv][0 * 64 + lane] = __expf(lrelu(a.x + d4.x));
                lw[wv][1 * 64 + lane] = __expf(lrelu(a.y + d4.y));
                lw[wv][2 * 64 + lane] = __expf(lrelu(a.z + d4.z));
                lw[wv][3 * 64 + lane] = __expf(lrelu(a.w + d4.w));
            }
            int i = 0;
            for (; i + 4 <= cnt; i += 4) {
                int4   s4  = *(const int4*)&ls[wv][i];
                float4 wx4 = *(const float4*)&lw[wv][h * 64 + i];
                ushort4 x0 = *(const ushort4*)(xb + ((unsigned)s4.x * 512u + loffb));
                ushort4 x1 = *(const ushort4*)(xb + ((unsigned)s4.y * 512u + loffb));
                ushort4 x2 = *(const ushort4*)(xb + ((unsigned)s4.z * 512u + loffb));
                ushort4 x3 = *(const ushort4*)(xb + ((unsigned)s4.w * 512u + loffb));
                dn += wx4.x + wx4.y + wx4.z + wx4.w;
                accA[0] += wx4.x * bf2f(x0.x); accA[1] += wx4.x * bf2f(x0.y);
                accA[2] += wx4.x * bf2f(x0.z); accA[3] += wx4.x * bf2f(x0.w);
                accB[0] += wx4.y * bf2f(x1.x); accB[1] += wx4.y * bf2f(x1.y);
                accB[2] += wx4.y * bf2f(x1.z); accB[3] += wx4.y * bf2f(x1.w);
                accA[0] += wx4.z * bf2f(x2.x); accA[1] += wx4.z * bf2f(x2.y);
                accA[2] += wx4.z * bf2f(x2.z); accA[3] += wx4.z * bf2f(x2.w);
                accB[0] += wx4.w * bf2f(x3.x); accB[1] += wx4.w * bf2f(x3.y);
                accB[2] += wx4.w * bf2f(x3.z); accB[3] += wx4.w * bf2f(x3.w);
            }
            for (; i < cnt; ++i) {
                int s = ls[wv][i];
                float wx = lw[wv][h * 64 + i];
                ushort4 xu = *(const ushort4*)(xb + ((unsigned)s * 512u + loffb));
                dn += wx;
                accA[0] += wx * bf2f(xu.x); accA[1] += wx * bf2f(xu.y);
                accA[2] += wx * bf2f(xu.z); accA[3] += wx * bf2f(xu.w);
            }
        }
    }

#pragma unroll
    for (int j = 0; j < 4; ++j) accA[j] += accB[j];
    float inv = 1.f / (dn + 1e-16f);
    ushort4 uo;
    uo.x = f2bf(fmaxf(accA[0] * inv, 0.f));
    uo.y = f2bf(fmaxf(accA[1] * inv, 0.f));
    uo.z = f2bf(fmaxf(accA[2] * inv, 0.f));
    uo.w = f2bf(fmaxf(accA[3] * inv, 0.f));
    *(ushort4*)&outb[(size_t)w * 256 + (lane << 2)] = uo;
}

__global__ void attn_k(const float* __restrict__ score, float* __restrict__ attn, float invN)
{
    if (threadIdx.x == 0 && blockIdx.x == 0) {
        float s0 = score[0] * invN, s1 = score[1] * invN;
        float m  = fmaxf(s0, s1);
        float e0 = expf(s0 - m), e1 = expf(s1 - m);
        float dsum = e0 + e1;
        attn[0] = e0 / dsum;
        attn[1] = e1 / dsum;
    }
}

extern "C" void kernel_launch(void* const* d_in, const int* in_sizes, int n_in,
                              void* d_out, int out_size, void* d_ws, size_t ws_size,
                              hipStream_t stream)
{
    const float* x_job    = (const float*)d_in[0];
    const float* x_skill  = (const float*)d_in[1];
    const float* W_job    = (const float*)d_in[2];
    const float* b_job    = (const float*)d_in[3];
    const float* W_skill  = (const float*)d_in[4];
    const float* b_skill  = (const float*)d_in[5];
    const float* a_src_sj = (const float*)d_in[6];
    const float* a_dst_sj = (const float*)d_in[7];
    const float* a_src_jj = (const float*)d_in[8];
    const float* a_dst_jj = (const float*)d_in[9];
    // d_in[10], d_in[11]: a_src_js / a_dst_js — js edge-type output unused by the head; skipped.
    const float* q_vec = (const float*)d_in[12];
    const float* Wk    = (const float*)d_in[13];
    const float* bk    = (const float*)d_in[14];
    const float* W1    = (const float*)d_in[15];
    const float* b1    = (const float*)d_in[16];
    const float* W2    = (const float*)d_in[17];
    const float* b2    = (const float*)d_in[18];
    const int* ei_sj_src = (const int*)d_in[19];
    const int* ei_sj_dst = (const int*)d_in[20];
    const int* ei_jj_src = (const int*)d_in[21];
    const int* ei_jj_dst = (const int*)d_in[22];

    const int NJ   = in_sizes[0] / 256;
    const int NS   = in_sizes[1] / 256;
    const int E_sj = in_sizes[19];
    const int E_jj = in_sizes[21];
    const int Emax = (E_sj > E_jj) ? E_sj : E_jj;
    const int gmJ  = (NJ + 127) / 128, gmS = (NS + 127) / 128;
    const long MpadJ = (long)gmJ * 128, MpadS = (long)gmS * 128;

    char* ws   = (char*)d_ws;
    size_t off = 0;
    auto alloc = [&](size_t bytes) { void* p = ws + off; off += (bytes + 255) & ~(size_t)255; return p; };
    unsigned short* h_job_bf   = (unsigned short*)alloc(MpadJ * 256 * 2);   // bf16 h tables
    unsigned short* h_skill_bf = (unsigned short*)alloc(MpadS * 256 * 2);
    unsigned short* Wjob_t  = (unsigned short*)alloc(256 * 256 * 2);
    unsigned short* Wskl_t  = (unsigned short*)alloc(256 * 256 * 2);
    unsigned short* Wk_t    = (unsigned short*)alloc(256 * 256 * 2);
    unsigned short* W1_t    = (unsigned short*)alloc(256 * 256 * 2);
    unsigned short* out_sj_bf = (unsigned short*)alloc(MpadJ * 256 * 2);
    unsigned short* out_jj_bf = (unsigned short*)alloc(MpadJ * 256 * 2);
    float* ald_sj  = (float*)alloc((size_t)NJ * 4 * 4);
    float* als_jj  = (float*)alloc((size_t)NJ * 4 * 4);
    float* ald_jj  = (float*)alloc((size_t)NJ * 4 * 4);
    float* als_sj  = (float*)alloc((size_t)NS * 4 * 4);
    float* score  = (float*)alloc(64 * 4);   // [0..1] raw scores, [2..3] attn
    float* attn   = score + 2;
    // CSR zero-region: deg/rp/part/cur contiguous -> single memset
    size_t zoff0 = off;
    int* deg_sj = (int*)alloc((size_t)NJ * 4);
    int* deg_jj = (int*)alloc((size_t)NJ * 4);
    int* rp_sj  = (int*)alloc(((size_t)NJ + 1) * 4);
    int* rp_jj  = (int*)alloc(((size_t)NJ + 1) * 4);
    int* part_a = (int*)alloc(1024 * 4);
    int* part_b = (int*)alloc(1024 * 4);
    int* cur_sj = (int*)alloc((size_t)NJ * 4);
    int* cur_jj = (int*)alloc((size_t)NJ * 4);
    size_t zoff1 = off;
    int* csr_sj = (int*)alloc((size_t)E_sj * 4);   // holds src node ids
    int* csr_jj = (int*)alloc((size_t)E_jj * 4);
    (void)ws_size; (void)n_in;

    hipMemsetAsync(score, 0, 2 * 4, stream);
    hipMemsetAsync(ws + zoff0, 0, zoff1 - zoff0, stream);   // deg/rp/part/cur in one shot

    dim3 blk(256);
    int nbJ = (NJ + SCAN_B - 1) / SCAN_B;

    // ---- weight transposes (one launch) ----
    transpose_cast4<<<dim3(256, 4), blk, 0, stream>>>(
        W_job, W_skill, Wk, W1, Wjob_t, Wskl_t, Wk_t, W1_t);

    // ---- CSR build (merged pairs; slots store src ids) ----
    hist2<<<dim3((Emax + 255) / 256, 2), blk, 0, stream>>>(
        ei_sj_dst, E_sj, deg_sj, ei_jj_dst, E_jj, deg_jj);
    scan_bsum2<<<dim3(nbJ, 2), dim3(SCAN_B), 0, stream>>>(deg_sj, deg_jj, NJ, part_a, part_b);
    scan_part2<<<dim3(1, 2), dim3(1024), 0, stream>>>(part_a, part_b, nbJ);
    scan_final2<<<dim3(nbJ, 2), dim3(SCAN_B), 0, stream>>>(
        deg_sj, deg_jj, NJ, part_a, part_b, rp_sj, rp_jj, E_sj, E_jj);
    fill_csr2<<<dim3((Emax + 255) / 256, 2), blk, 0, stream>>>(
        ei_sj_dst, ei_sj_src, E_sj, rp_sj, cur_sj, csr_sj,
        ei_jj_dst, ei_jj_src, E_jj, rp_jj, cur_jj, csr_jj);

    // ---- input projections (pipelined MFMA, f32 cast in-stage) + fused logits ----
    gemm_mfma<0, 3, 1><<<dim3(gmJ), dim3(512), 0, stream>>>(
        x_job, nullptr, nullptr, Wjob_t, b_job, nullptr, nullptr, nullptr,
        h_job_bf, nullptr, nullptr,
        a_dst_sj, a_src_jj, a_dst_jj, ald_sj, als_jj, ald_jj, NJ);
    gemm_mfma<0, 1, 1><<<dim3(gmS), dim3(512), 0, stream>>>(
        x_skill, nullptr, nullptr, Wskl_t, b_skill, nullptr, nullptr, nullptr,
        h_skill_bf, nullptr, nullptr,
        a_src_sj, nullptr, nullptr, als_sj, nullptr, nullptr, NS);

    // ---- fused per-dst GAT, both edge types in one launch ----
    gat_fused<<<dim3((NJ + 3) / 4, 2), blk, 0, stream>>>(
        h_skill_bf, h_job_bf, als_sj, als_jj, ald_sj, ald_jj,
        rp_sj, rp_jj, csr_sj, csr_jj, NJ,
        out_sj_bf, out_jj_bf);

    // ---- semantic attention scores (both types in one launch) ----
    gemm_mfma<1, 0, 0><<<dim3(gmJ, 2), dim3(512), 0, stream>>>(
        nullptr, out_sj_bf, out_jj_bf, Wk_t, bk, q_vec, nullptr, nullptr,
        nullptr, nullptr, score,
        nullptr, nullptr, nullptr, nullptr, nullptr, nullptr, NJ);
    attn_k<<<1, 64, 0, stream>>>(score, attn, 1.0f / (float)NJ);

    // ---- head: blend fused into A-staging; relu+W2-dot+b2 epilogue ----
    gemm_mfma<2, 0, 0><<<dim3(gmJ), dim3(512), 0, stream>>>(
        nullptr, out_sj_bf, out_jj_bf, W1_t, b1, W2, b2, attn,
        nullptr, (float*)d_out, nullptr,
        nullptr, nullptr, nullptr, nullptr, nullptr, nullptr, NJ);
}

// Round 16
// 394.050 us; speedup vs baseline: 2.1492x; 2.1492x over previous
//
#include <hip/hip_runtime.h>
#include <hip/hip_bf16.h>
#include <math.h>

#define SCAN_B 256

typedef __attribute__((ext_vector_type(8))) short bf16x8;   // 8 bf16 = 4 VGPR
typedef __attribute__((ext_vector_type(4))) float f32x4;

__device__ __forceinline__ unsigned short f2bf(float f) {
    __hip_bfloat16 h = __float2bfloat16(f);   // RNE
    return *(unsigned short*)&h;
}
__device__ __forceinline__ float bf2f(unsigned short u) {
    unsigned v = ((unsigned)u) << 16;
    return __uint_as_float(v);
}
__device__ __forceinline__ float lrelu(float x) { return (x >= 0.f) ? x : 0.2f * x; }

// blend two packed bf16 pairs: r = bf16(c0*a + c1*b) lane-wise
__device__ __forceinline__ unsigned blend2(unsigned a, unsigned b, float c0, float c1) {
    float alo = bf2f((unsigned short)(a & 0xffff)), ahi = bf2f((unsigned short)(a >> 16));
    float blo = bf2f((unsigned short)(b & 0xffff)), bhi = bf2f((unsigned short)(b >> 16));
    unsigned short rlo = f2bf(c0 * alo + c1 * blo);
    unsigned short rhi = f2bf(c0 * ahi + c1 * bhi);
    return (unsigned)rlo | ((unsigned)rhi << 16);
}

// =============== MFMA GEMM: A[*,256] @ B^T[256n,256k]bf16 ===============
// (R14-proven body: 128x256 tile, BK=64, single-buffered 48KB LDS, VGPR 72.)
// AF32: A is f32, converted to bf16 during LDS staging (fuses the cast kernel).
// MODE 0: outh[M,256] = bf16(A@B + bias); fused per-head logits lo_v (head = wc)
// MODE 1: A selected by blockIdx.y; atomicAdd(scoreSlot[y], sum_rows q.tanh(A@B+bias))
// MODE 2: A' = bf16(attn0*A + attn1*A2) at stage time; outf[row] = relu-dot + b2
template<int MODE, int NV, int AF32>
__launch_bounds__(512)
__global__ void gemm_mfma(const float* __restrict__ Af32,
                          const unsigned short* __restrict__ Abf,
                          const unsigned short* __restrict__ A2bf,
                          const unsigned short* __restrict__ Bt,
                          const float* __restrict__ bias,
                          const float* __restrict__ vq,
                          const float* __restrict__ b2p,
                          const float* __restrict__ attn2,
                          unsigned short* __restrict__ outh,
                          float* __restrict__ outf,
                          float* __restrict__ scoreSlot,
                          const float* __restrict__ av0,
                          const float* __restrict__ av1,
                          const float* __restrict__ av2,
                          float* __restrict__ lo0,
                          float* __restrict__ lo1,
                          float* __restrict__ lo2,
                          int M)
{
    __shared__ __align__(16) char sm[49152];   // A:[0,16K)=[128][64]bf16; B^T:[16K,48K)=[256][64]bf16
    __shared__ float red8[8];
    const int t    = threadIdx.x;
    const int lane = t & 63, wid = t >> 6;
    const int wr = wid >> 2, wc = wid & 3;
    const long row0 = (long)blockIdx.x * 128;
    const char* Ab = (const char*)((MODE == 1 && blockIdx.y == 1) ? A2bf : Abf);
    const char* A2 = (const char*)A2bf;
    const char* Bb = (const char*)Bt;

    float blend0 = 0.f, blend1 = 0.f;
    if (MODE == 2) { blend0 = attn2[0]; blend1 = attn2[1]; }

    f32x4 acc[4][4];
#pragma unroll
    for (int m = 0; m < 4; ++m)
#pragma unroll
        for (int n = 0; n < 4; ++n) acc[m][n] = (f32x4){0.f, 0.f, 0.f, 0.f};

    for (int k0 = 0; k0 < 256; k0 += 64) {
#pragma unroll
        for (int rep = 0; rep < 2; ++rep) {
            int idx = rep * 512 + t;
            int row = idx >> 3, colb = (idx & 7) << 4;
            uint4 v;
            if (AF32) {
                long grow = row0 + row;
                if (grow < M) {
                    const float* sp = Af32 + grow * 256 + k0 + ((idx & 7) << 3);
                    float4 f0 = *(const float4*)sp;
                    float4 f1 = *(const float4*)(sp + 4);
                    v.x = (unsigned)f2bf(f0.x) | ((unsigned)f2bf(f0.y) << 16);
                    v.y = (unsigned)f2bf(f0.z) | ((unsigned)f2bf(f0.w) << 16);
                    v.z = (unsigned)f2bf(f1.x) | ((unsigned)f2bf(f1.y) << 16);
                    v.w = (unsigned)f2bf(f1.z) | ((unsigned)f2bf(f1.w) << 16);
                } else {
                    v = make_uint4(0u, 0u, 0u, 0u);
                }
            } else {
                v = *(const uint4*)(Ab + (row0 + row) * 512 + k0 * 2 + colb);
                if (MODE == 2) {
                    uint4 v2 = *(const uint4*)(A2 + (row0 + row) * 512 + k0 * 2 + colb);
                    v.x = blend2(v.x, v2.x, blend0, blend1);
                    v.y = blend2(v.y, v2.y, blend0, blend1);
                    v.z = blend2(v.z, v2.z, blend0, blend1);
                    v.w = blend2(v.w, v2.w, blend0, blend1);
                }
            }
            *(uint4*)&sm[row * 128 + (colb ^ ((row & 7) << 4))] = v;
        }
#pragma unroll
        for (int rep = 0; rep < 4; ++rep) {
            int idx = rep * 512 + t;
            int n = idx >> 3, colb = (idx & 7) << 4;
            uint4 v = *(const uint4*)(Bb + n * 512 + k0 * 2 + colb);
            *(uint4*)&sm[16384 + n * 128 + (colb ^ ((n & 7) << 4))] = v;
        }
        __syncthreads();
#pragma unroll
        for (int kki = 0; kki < 2; ++kki) {
            const int kb = kki * 64 + ((lane >> 4) << 4);
            bf16x8 a[4], b[4];
#pragma unroll
            for (int m = 0; m < 4; ++m) {
                int row = wr * 64 + m * 16 + (lane & 15);
                a[m] = *(const bf16x8*)&sm[row * 128 + (kb ^ ((row & 7) << 4))];
            }
#pragma unroll
            for (int n = 0; n < 4; ++n) {
                int nr = wc * 64 + n * 16 + (lane & 15);
                b[n] = *(const bf16x8*)&sm[16384 + nr * 128 + (kb ^ ((nr & 7) << 4))];
            }
#pragma unroll
            for (int m = 0; m < 4; ++m)
#pragma unroll
                for (int n = 0; n < 4; ++n)
                    acc[m][n] = __builtin_amdgcn_mfma_f32_16x16x32_bf16(a[m], b[n], acc[m][n], 0, 0, 0);
        }
        __syncthreads();
    }

    const int colbase = wc * 64 + (lane & 15);
    const int rbase   = wr * 64 + ((lane >> 4) << 2);
    float bv[4];
#pragma unroll
    for (int n = 0; n < 4; ++n) bv[n] = bias[colbase + n * 16];

    if (MODE == 0) {
        float areg[(NV > 0) ? NV : 1][4];
#pragma unroll
        for (int v = 0; v < NV; ++v) {
            const float* av = (v == 0) ? av0 : (v == 1) ? av1 : av2;
#pragma unroll
            for (int n = 0; n < 4; ++n) areg[v][n] = av[colbase + n * 16];
        }
#pragma unroll
        for (int m = 0; m < 4; ++m) {
#pragma unroll
            for (int j = 0; j < 4; ++j) {
                long row = row0 + rbase + m * 16 + j;
                float hv[4];
#pragma unroll
                for (int n = 0; n < 4; ++n) hv[n] = acc[m][n][j] + bv[n];
                if (row < M) {
#pragma unroll
                    for (int n = 0; n < 4; ++n)
                        outh[row * 256 + colbase + n * 16] = f2bf(hv[n]);
                }
#pragma unroll
                for (int v = 0; v < NV; ++v) {
                    float p = hv[0] * areg[v][0] + hv[1] * areg[v][1]
                            + hv[2] * areg[v][2] + hv[3] * areg[v][3];
                    p += __shfl_xor(p, 1); p += __shfl_xor(p, 2);
                    p += __shfl_xor(p, 4); p += __shfl_xor(p, 8);
                    if ((lane & 15) == 0 && row < M) {
                        float* lo = (v == 0) ? lo0 : (v == 1) ? lo1 : lo2;
                        lo[row * 4 + wc] = p;
                    }
                }
            }
        }
    } else if (MODE == 1) {
        float p = 0.f;
        float qv[4];
#pragma unroll
        for (int n = 0; n < 4; ++n) qv[n] = vq[colbase + n * 16];
#pragma unroll
        for (int n = 0; n < 4; ++n) {
#pragma unroll
            for (int m = 0; m < 4; ++m) {
                long row = row0 + rbase + m * 16;
#pragma unroll
                for (int j = 0; j < 4; ++j)
                    if (row + j < M) p += qv[n] * tanhf(acc[m][n][j] + bv[n]);
            }
        }
#pragma unroll
        for (int off = 32; off > 0; off >>= 1) p += __shfl_xor(p, off);
        if (lane == 0) red8[wid] = p;
        __syncthreads();
        if (t == 0) {
            float s = 0.f;
#pragma unroll
            for (int i = 0; i < 8; ++i) s += red8[i];
            atomicAdd(&scoreSlot[blockIdx.y], s);
        }
    } else {
        float* redC = (float*)sm;   // reuse tile buffer (free after final barrier)
        float b2v = b2p[0];
        float wv[4];
#pragma unroll
        for (int n = 0; n < 4; ++n) wv[n] = vq[colbase + n * 16];
#pragma unroll
        for (int m = 0; m < 4; ++m) {
#pragma unroll
            for (int j = 0; j < 4; ++j) {
                float s = 0.f;
#pragma unroll
                for (int n = 0; n < 4; ++n)
                    s += fmaxf(acc[m][n][j] + bv[n], 0.f) * wv[n];
                s += __shfl_xor(s, 1); s += __shfl_xor(s, 2);
                s += __shfl_xor(s, 4); s += __shfl_xor(s, 8);
                if ((lane & 15) == 0) {
                    int lrow = wr * 64 + m * 16 + ((lane >> 4) << 2) + j;
                    redC[lrow * 4 + wc] = s;
                }
            }
        }
        __syncthreads();
        if (t < 128) {
            long row = row0 + t;
            if (row < M)
                outf[row] = redC[t * 4 + 0] + redC[t * 4 + 1]
                          + redC[t * 4 + 2] + redC[t * 4 + 3] + b2v;
        }
    }
}

// ---------------- merged weight transposes: Wt[n][k] = bf16(W[k][n]) ----------------
__global__ void transpose_cast4(const float* __restrict__ W0, const float* __restrict__ W1s,
                                const float* __restrict__ W2s, const float* __restrict__ W3s,
                                unsigned short* __restrict__ T0, unsigned short* __restrict__ T1,
                                unsigned short* __restrict__ T2, unsigned short* __restrict__ T3)
{
    const float* W = (blockIdx.y == 0) ? W0 : (blockIdx.y == 1) ? W1s : (blockIdx.y == 2) ? W2s : W3s;
    unsigned short* T = (blockIdx.y == 0) ? T0 : (blockIdx.y == 1) ? T1 : (blockIdx.y == 2) ? T2 : T3;
    int n = blockIdx.x, k = threadIdx.x;
    T[n * 256 + k] = f2bf(W[k * 256 + n]);
}

// ---------------- CSR build (both edge types via blockIdx.y) ----------------
__global__ void hist2(const int* __restrict__ d0, int E0, int* __restrict__ g0,
                      const int* __restrict__ d1, int E1, int* __restrict__ g1)
{
    int e = blockIdx.x * 256 + threadIdx.x;
    if (blockIdx.y == 0) { if (e < E0) atomicAdd(&g0[d0[e]], 1); }
    else                 { if (e < E1) atomicAdd(&g1[d1[e]], 1); }
}

__global__ void scan_bsum2(const int* __restrict__ g0, const int* __restrict__ g1, int n,
                           int* __restrict__ p0, int* __restrict__ p1)
{
    const int* deg = blockIdx.y ? g1 : g0;
    int* part      = blockIdx.y ? p1 : p0;
    __shared__ int smem[SCAN_B];
    int i = blockIdx.x * SCAN_B + threadIdx.x;
    smem[threadIdx.x] = (i < n) ? deg[i] : 0;
    __syncthreads();
    for (int off = SCAN_B / 2; off > 0; off >>= 1) {
        if (threadIdx.x < off) smem[threadIdx.x] += smem[threadIdx.x + off];
        __syncthreads();
    }
    if (threadIdx.x == 0) part[blockIdx.x] = smem[0];
}

__global__ void scan_part2(int* __restrict__ p0, int* __restrict__ p1, int nb)
{
    int* part = blockIdx.y ? p1 : p0;
    __shared__ int smem[1024];
    int t = threadIdx.x;
    int v = (t < nb) ? part[t] : 0;
    smem[t] = v;
    __syncthreads();
    for (int off = 1; off < 1024; off <<= 1) {
        int add = (t >= off) ? smem[t - off] : 0;
        __syncthreads();
        smem[t] += add;
        __syncthreads();
    }
    if (t < nb) part[t] = smem[t] - v;
}

__global__ void scan_final2(const int* __restrict__ g0, const int* __restrict__ g1, int n,
                            const int* __restrict__ p0, const int* __restrict__ p1,
                            int* __restrict__ r0, int* __restrict__ r1, int E0, int E1)
{
    const int* deg = blockIdx.y ? g1 : g0;
    const int* part = blockIdx.y ? p1 : p0;
    int* rowptr = blockIdx.y ? r1 : r0;
    int E = blockIdx.y ? E1 : E0;
    __shared__ int smem[SCAN_B];
    int t = threadIdx.x;
    int i = blockIdx.x * SCAN_B + t;
    int v = (i < n) ? deg[i] : 0;
    smem[t] = v;
    __syncthreads();
    for (int off = 1; off < SCAN_B; off <<= 1) {
        int add = (t >= off) ? smem[t - off] : 0;
        __syncthreads();
        smem[t] += add;
        __syncthreads();
    }
    if (i < n) rowptr[i] = part[blockIdx.x] + smem[t] - v;
    if (blockIdx.x == 0 && t == 0) rowptr[n] = E;
}

// fill CSR slots with the SOURCE NODE ID directly (not the edge id)
__global__ void fill_csr2(const int* __restrict__ d0, const int* __restrict__ s0arr, int E0,
                          const int* __restrict__ r0, int* __restrict__ c0, int* __restrict__ o0,
                          const int* __restrict__ d1, const int* __restrict__ s1arr, int E1,
                          const int* __restrict__ r1, int* __restrict__ c1, int* __restrict__ o1)
{
    int e = blockIdx.x * 256 + threadIdx.x;
    if (blockIdx.y == 0) {
        if (e < E0) { int d = d0[e]; int s = atomicAdd(&c0[d], 1); o0[r0[d] + s] = s0arr[e]; }
    } else {
        if (e < E1) { int d = d1[e]; int s = atomicAdd(&c1[d], 1); o1[r1[d] + s] = s1arr[e]; }
    }
}

// ======== fused per-dst GAT (merged over gridDim.y = 2 edge types) ========
// one wave per dst node; bf16 x tables; CSR slots hold src ids (2-deep chain).
// NO-MAX softmax (logits bounded); denominator folded into the gather loop.
// lw stored TRANSPOSED [head][edge]; 4-edge inner loop reads 4 weights + 4 src
// ids as two ds_read_b128 (16-lane broadcast groups).
__launch_bounds__(256)
__global__ void gat_fused(const unsigned short* __restrict__ xs0,
                          const unsigned short* __restrict__ xs1,
                          const float* __restrict__ als0, const float* __restrict__ als1,
                          const float* __restrict__ ald0, const float* __restrict__ ald1,
                          const int* __restrict__ rp0, const int* __restrict__ rp1,
                          const int* __restrict__ csr0, const int* __restrict__ csr1,
                          int N,
                          unsigned short* __restrict__ out0,
                          unsigned short* __restrict__ out1)
{
    const int et = blockIdx.y;
    const unsigned short* xsrc = et ? xs1 : xs0;
    const float* als = et ? als1 : als0;
    const float* ald = et ? ald1 : ald0;
    const int* rowptr = et ? rp1 : rp0;
    const int* csr    = et ? csr1 : csr0;
    unsigned short* outb = et ? out1 : out0;

    __shared__ __align__(16) float lw[4][4 * 64];   // [wave][head*64 + edge]
    __shared__ __align__(16) int   ls[4][64];
    const int wv   = threadIdx.x >> 6;
    const int w    = (int)((blockIdx.x * 256 + threadIdx.x) >> 6);
    const int lane = threadIdx.x & 63;
    if (w >= N) return;
    const int beg = rowptr[w], end = rowptr[w + 1];
    const int deg = end - beg;
    const int h = lane >> 4;
    const float4 d4 = *(const float4*)&ald[(size_t)w * 4];
    const unsigned loffb = (unsigned)(lane << 3);          // byte offset of lane's 4 bf16
    const char* xb = (const char*)xsrc;

    float accA[4] = {0.f, 0.f, 0.f, 0.f};
    float accB[4] = {0.f, 0.f, 0.f, 0.f};
    float dn = 0.f;

    if (deg <= 64) {
        if (lane < deg) {
            int es = csr[beg + lane];                 // src id directly
            float4 a = *(const float4*)&als[(size_t)es * 4];
            ls[wv][lane] = es;
            lw[wv][0 * 64 + lane] = __expf(lrelu(a.x + d4.x));
            lw[wv][1 * 64 + lane] = __expf(lrelu(a.y + d4.y));
            lw[wv][2 * 64 + lane] = __expf(lrelu(a.z + d4.z));
            lw[wv][3 * 64 + lane] = __expf(lrelu(a.w + d4.w));
        }
        int i = 0;
        for (; i + 4 <= deg; i += 4) {
            int4   s4  = *(const int4*)&ls[wv][i];
            float4 wx4 = *(const float4*)&lw[wv][h * 64 + i];
            ushort4 x0 = *(const ushort4*)(xb + ((unsigned)s4.x * 512u + loffb));
            ushort4 x1 = *(const ushort4*)(xb + ((unsigned)s4.y * 512u + loffb));
            ushort4 x2 = *(const ushort4*)(xb + ((unsigned)s4.z * 512u + loffb));
            ushort4 x3 = *(const ushort4*)(xb + ((unsigned)s4.w * 512u + loffb));
            dn += wx4.x + wx4.y + wx4.z + wx4.w;
            accA[0] += wx4.x * bf2f(x0.x); accA[1] += wx4.x * bf2f(x0.y);
            accA[2] += wx4.x * bf2f(x0.z); accA[3] += wx4.x * bf2f(x0.w);
            accB[0] += wx4.y * bf2f(x1.x); accB[1] += wx4.y * bf2f(x1.y);
            accB[2] += wx4.y * bf2f(x1.z); accB[3] += wx4.y * bf2f(x1.w);
            accA[0] += wx4.z * bf2f(x2.x); accA[1] += wx4.z * bf2f(x2.y);
            accA[2] += wx4.z * bf2f(x2.z); accA[3] += wx4.z * bf2f(x2.w);
            accB[0] += wx4.w * bf2f(x3.x); accB[1] += wx4.w * bf2f(x3.y);
            accB[2] += wx4.w * bf2f(x3.z); accB[3] += wx4.w * bf2f(x3.w);
        }
        for (; i < deg; ++i) {
            int s = ls[wv][i];
            float wx = lw[wv][h * 64 + i];
            ushort4 xu = *(const ushort4*)(xb + ((unsigned)s * 512u + loffb));
            dn += wx;
            accA[0] += wx * bf2f(xu.x); accA[1] += wx * bf2f(xu.y);
            accA[2] += wx * bf2f(xu.z); accA[3] += wx * bf2f(xu.w);
        }
    } else {
        for (int c = beg; c < end; c += 64) {
            int cnt = min(64, end - c);
            if (lane < cnt) {
                int es = csr[c + lane];
                float4 a = *(const float4*)&als[(size_t)es * 4];
                ls[wv][lane] = es;
                lw[wv][0 * 64 + lane] = __expf(lrelu(a.x + d4.x));
                lw[wv][1 * 64 + lane] = __expf(lrelu(a.y + d4.y));
                lw[wv][2 * 64 + lane] = __expf(lrelu(a.z + d4.z));
                lw[wv][3 * 64 + lane] = __expf(lrelu(a.w + d4.w));
            }
            int i = 0;
            for (; i + 4 <= cnt; i += 4) {
                int4   s4  = *(const int4*)&ls[wv][i];
                float4 wx4 = *(const float4*)&lw[wv][h * 64 + i];
                ushort4 x0 = *(const ushort4*)(xb + ((unsigned)s4.x * 512u + loffb));
                ushort4 x1 = *(const ushort4*)(xb + ((unsigned)s4.y * 512u + loffb));
                ushort4 x2 = *(const ushort4*)(xb + ((unsigned)s4.z * 512u + loffb));
                ushort4 x3 = *(const ushort4*)(xb + ((unsigned)s4.w * 512u + loffb));
                dn += wx4.x + wx4.y + wx4.z + wx4.w;
                accA[0] += wx4.x * bf2f(x0.x); accA[1] += wx4.x * bf2f(x0.y);
                accA[2] += wx4.x * bf2f(x0.z); accA[3] += wx4.x * bf2f(x0.w);
                accB[0] += wx4.y * bf2f(x1.x); accB[1] += wx4.y * bf2f(x1.y);
                accB[2] += wx4.y * bf2f(x1.z); accB[3] += wx4.y * bf2f(x1.w);
                accA[0] += wx4.z * bf2f(x2.x); accA[1] += wx4.z * bf2f(x2.y);
                accA[2] += wx4.z * bf2f(x2.z); accA[3] += wx4.z * bf2f(x2.w);
                accB[0] += wx4.w * bf2f(x3.x); accB[1] += wx4.w * bf2f(x3.y);
                accB[2] += wx4.w * bf2f(x3.z); accB[3] += wx4.w * bf2f(x3.w);
            }
            for (; i < cnt; ++i) {
                int s = ls[wv][i];
                float wx = lw[wv][h * 64 + i];
                ushort4 xu = *(const ushort4*)(xb + ((unsigned)s * 512u + loffb));
                dn += wx;
                accA[0] += wx * bf2f(xu.x); accA[1] += wx * bf2f(xu.y);
                accA[2] += wx * bf2f(xu.z); accA[3] += wx * bf2f(xu.w);
            }
        }
    }

#pragma unroll
    for (int j = 0; j < 4; ++j) accA[j] += accB[j];
    float inv = 1.f / (dn + 1e-16f);
    ushort4 uo;
    uo.x = f2bf(fmaxf(accA[0] * inv, 0.f));
    uo.y = f2bf(fmaxf(accA[1] * inv, 0.f));
    uo.z = f2bf(fmaxf(accA[2] * inv, 0.f));
    uo.w = f2bf(fmaxf(accA[3] * inv, 0.f));
    *(ushort4*)&outb[(size_t)w * 256 + (lane << 2)] = uo;
}

__global__ void attn_k(const float* __restrict__ score, float* __restrict__ attn, float invN)
{
    if (threadIdx.x == 0 && blockIdx.x == 0) {
        float s0 = score[0] * invN, s1 = score[1] * invN;
        float m  = fmaxf(s0, s1);
        float e0 = expf(s0 - m), e1 = expf(s1 - m);
        float dsum = e0 + e1;
        attn[0] = e0 / dsum;
        attn[1] = e1 / dsum;
    }
}

extern "C" void kernel_launch(void* const* d_in, const int* in_sizes, int n_in,
                              void* d_out, int out_size, void* d_ws, size_t ws_size,
                              hipStream_t stream)
{
    const float* x_job    = (const float*)d_in[0];
    const float* x_skill  = (const float*)d_in[1];
    const float* W_job    = (const float*)d_in[2];
    const float* b_job    = (const float*)d_in[3];
    const float* W_skill  = (const float*)d_in[4];
    const float* b_skill  = (const float*)d_in[5];
    const float* a_src_sj = (const float*)d_in[6];
    const float* a_dst_sj = (const float*)d_in[7];
    const float* a_src_jj = (const float*)d_in[8];
    const float* a_dst_jj = (const float*)d_in[9];
    // d_in[10], d_in[11]: a_src_js / a_dst_js — js edge-type output unused by the head; skipped.
    const float* q_vec = (const float*)d_in[12];
    const float* Wk    = (const float*)d_in[13];
    const float* bk    = (const float*)d_in[14];
    const float* W1    = (const float*)d_in[15];
    const float* b1    = (const float*)d_in[16];
    const float* W2    = (const float*)d_in[17];
    const float* b2    = (const float*)d_in[18];
    const int* ei_sj_src = (const int*)d_in[19];
    const int* ei_sj_dst = (const int*)d_in[20];
    const int* ei_jj_src = (const int*)d_in[21];
    const int* ei_jj_dst = (const int*)d_in[22];

    const int NJ   = in_sizes[0] / 256;
    const int NS   = in_sizes[1] / 256;
    const int E_sj = in_sizes[19];
    const int E_jj = in_sizes[21];
    const int Emax = (E_sj > E_jj) ? E_sj : E_jj;
    const int gmJ  = (NJ + 127) / 128, gmS = (NS + 127) / 128;
    const long MpadJ = (long)gmJ * 128, MpadS = (long)gmS * 128;

    char* ws   = (char*)d_ws;
    size_t off = 0;
    auto alloc = [&](size_t bytes) { void* p = ws + off; off += (bytes + 255) & ~(size_t)255; return p; };
    unsigned short* h_job_bf   = (unsigned short*)alloc(MpadJ * 256 * 2);   // bf16 h tables
    unsigned short* h_skill_bf = (unsigned short*)alloc(MpadS * 256 * 2);
    unsigned short* Wjob_t  = (unsigned short*)alloc(256 * 256 * 2);
    unsigned short* Wskl_t  = (unsigned short*)alloc(256 * 256 * 2);
    unsigned short* Wk_t    = (unsigned short*)alloc(256 * 256 * 2);
    unsigned short* W1_t    = (unsigned short*)alloc(256 * 256 * 2);
    unsigned short* out_sj_bf = (unsigned short*)alloc(MpadJ * 256 * 2);
    unsigned short* out_jj_bf = (unsigned short*)alloc(MpadJ * 256 * 2);
    float* ald_sj  = (float*)alloc((size_t)NJ * 4 * 4);
    float* als_jj  = (float*)alloc((size_t)NJ * 4 * 4);
    float* ald_jj  = (float*)alloc((size_t)NJ * 4 * 4);
    float* als_sj  = (float*)alloc((size_t)NS * 4 * 4);
    float* score  = (float*)alloc(64 * 4);   // [0..1] raw scores, [2..3] attn
    float* attn   = score + 2;
    // CSR zero-region: deg/rp/part/cur contiguous -> single memset
    size_t zoff0 = off;
    int* deg_sj = (int*)alloc((size_t)NJ * 4);
    int* deg_jj = (int*)alloc((size_t)NJ * 4);
    int* rp_sj  = (int*)alloc(((size_t)NJ + 1) * 4);
    int* rp_jj  = (int*)alloc(((size_t)NJ + 1) * 4);
    int* part_a = (int*)alloc(1024 * 4);
    int* part_b = (int*)alloc(1024 * 4);
    int* cur_sj = (int*)alloc((size_t)NJ * 4);
    int* cur_jj = (int*)alloc((size_t)NJ * 4);
    size_t zoff1 = off;
    int* csr_sj = (int*)alloc((size_t)E_sj * 4);   // holds src node ids
    int* csr_jj = (int*)alloc((size_t)E_jj * 4);
    (void)ws_size; (void)n_in;

    hipMemsetAsync(score, 0, 2 * 4, stream);
    hipMemsetAsync(ws + zoff0, 0, zoff1 - zoff0, stream);   // deg/rp/part/cur in one shot

    dim3 blk(256);
    int nbJ = (NJ + SCAN_B - 1) / SCAN_B;

    // ---- weight transposes (one launch) ----
    transpose_cast4<<<dim3(256, 4), blk, 0, stream>>>(
        W_job, W_skill, Wk, W1, Wjob_t, Wskl_t, Wk_t, W1_t);

    // ---- CSR build (merged pairs; slots store src ids) ----
    hist2<<<dim3((Emax + 255) / 256, 2), blk, 0, stream>>>(
        ei_sj_dst, E_sj, deg_sj, ei_jj_dst, E_jj, deg_jj);
    scan_bsum2<<<dim3(nbJ, 2), dim3(SCAN_B), 0, stream>>>(deg_sj, deg_jj, NJ, part_a, part_b);
    scan_part2<<<dim3(1, 2), dim3(1024), 0, stream>>>(part_a, part_b, nbJ);
    scan_final2<<<dim3(nbJ, 2), dim3(SCAN_B), 0, stream>>>(
        deg_sj, deg_jj, NJ, part_a, part_b, rp_sj, rp_jj, E_sj, E_jj);
    fill_csr2<<<dim3((Emax + 255) / 256, 2), blk, 0, stream>>>(
        ei_sj_dst, ei_sj_src, E_sj, rp_sj, cur_sj, csr_sj,
        ei_jj_dst, ei_jj_src, E_jj, rp_jj, cur_jj, csr_jj);

    // ---- input projections (MFMA, f32 A staged+cast in-kernel) + fused logits ----
    gemm_mfma<0, 3, 1><<<dim3(gmJ), dim3(512), 0, stream>>>(
        x_job, nullptr, nullptr, Wjob_t, b_job, nullptr, nullptr, nullptr,
        h_job_bf, nullptr, nullptr,
        a_dst_sj, a_src_jj, a_dst_jj, ald_sj, als_jj, ald_jj, NJ);
    gemm_mfma<0, 1, 1><<<dim3(gmS), dim3(512), 0, stream>>>(
        x_skill, nullptr, nullptr, Wskl_t, b_skill, nullptr, nullptr, nullptr,
        h_skill_bf, nullptr, nullptr,
        a_src_sj, nullptr, nullptr, als_sj, nullptr, nullptr, NS);

    // ---- fused per-dst GAT, both edge types in one launch ----
    gat_fused<<<dim3((NJ + 3) / 4, 2), blk, 0, stream>>>(
        h_skill_bf, h_job_bf, als_sj, als_jj, ald_sj, ald_jj,
        rp_sj, rp_jj, csr_sj, csr_jj, NJ,
        out_sj_bf, out_jj_bf);

    // ---- semantic attention scores (both types in one launch) ----
    gemm_mfma<1, 0, 0><<<dim3(gmJ, 2), dim3(512), 0, stream>>>(
        nullptr, out_sj_bf, out_jj_bf, Wk_t, bk, q_vec, nullptr, nullptr,
        nullptr, nullptr, score,
        nullptr, nullptr, nullptr, nullptr, nullptr, nullptr, NJ);
    attn_k<<<1, 64, 0, stream>>>(score, attn, 1.0f / (float)NJ);

    // ---- head: blend fused into A-staging; relu+W2-dot+b2 epilogue ----
    gemm_mfma<2, 0, 0><<<dim3(gmJ), dim3(512), 0, stream>>>(
        nullptr, out_sj_bf, out_jj_bf, W1_t, b1, W2, b2, attn,
        nullptr, (float*)d_out, nullptr,
        nullptr, nullptr, nullptr, nullptr, nullptr, nullptr, NJ);
}